// Round 6
// baseline (1904.377 us; speedup 1.0000x reference)
//
#include <hip/hip_runtime.h>
#include <hip/hip_bf16.h>

#define T_DIM 256
#define B_DIM 256
#define E_DIM 256
#define H_DIM 512
#define V_DIM 50257

typedef __attribute__((ext_vector_type(8))) short short8;
typedef __attribute__((ext_vector_type(4))) float f32x4;
typedef __attribute__((ext_vector_type(2))) unsigned int uint2v;

__device__ __forceinline__ unsigned short f2bf(float f) {
    union { float f; unsigned u; } v; v.f = f;
    unsigned r = v.u + 0x7FFFu + ((v.u >> 16) & 1u);
    return (unsigned short)(r >> 16);
}
__device__ __forceinline__ short cvt_bf(float f) { return (short)f2bf(f); }
__device__ __forceinline__ float sigmoidf_(float x) {
    return 1.0f / (1.0f + __expf(-x));
}
__device__ __forceinline__ float tanhf_(float x) {
    float xc = fminf(fmaxf(x, -15.0f), 15.0f);
    float e = __expf(2.0f * xc);
    return (e - 1.0f) / (e + 1.0f);
}

// ---- dual-path coherent accessors -----------------------------------------
// LOCAL path: plain stores write through L1 into the producer's XCD L2; sc0
// loads bypass (possibly stale) L1 and read that same L2. Valid ONLY when
// producer and consumer share an XCD — proven fresh cross-CU by R2/R3 runs.
// MALL path: sc0 sc1 ops meet at the memory-side Infinity Cache — valid for
// ANY placement (R3 semantics). Producers publish on BOTH paths; consumers
// try LOCAL briefly, then fall back to MALL. No waits can deadlock: the MALL
// copy always arrives. Loads return in-flight; callers must s_waitcnt +
// sched_barrier(0) before use (rule #18).
__device__ __forceinline__ short8 load16_loc(const unsigned short* p) {
    short8 r;
    asm volatile("global_load_dwordx4 %0, %1, off sc0"
                 : "=v"(r) : "v"(p) : "memory");
    return r;
}
__device__ __forceinline__ short8 load16_mall(const unsigned short* p) {
    short8 r;
    asm volatile("global_load_dwordx4 %0, %1, off sc0 sc1"
                 : "=v"(r) : "v"(p) : "memory");
    return r;
}
__device__ __forceinline__ int load_flag_loc(const int* p) {
    int r;
    asm volatile("global_load_dword %0, %1, off sc0\n\t"
                 "s_waitcnt vmcnt(0)"
                 : "=v"(r) : "v"(p) : "memory");
    return r;
}
__device__ __forceinline__ int load_flag_mall(const int* p) {
    int r;
    asm volatile("global_load_dword %0, %1, off sc0 sc1\n\t"
                 "s_waitcnt vmcnt(0)"
                 : "=v"(r) : "v"(p) : "memory");
    return r;
}
__device__ __forceinline__ void store8_loc(unsigned short* p, uint2v v) {
    asm volatile("global_store_dwordx2 %0, %1, off"
                 :: "v"(p), "v"(v) : "memory");
}
__device__ __forceinline__ void store8_mall(unsigned short* p, uint2v v) {
    asm volatile("global_store_dwordx2 %0, %1, off sc0 sc1"
                 :: "v"(p), "v"(v) : "memory");
}
__device__ __forceinline__ void store_flag_loc(int* p, int v) {
    asm volatile("global_store_dword %0, %1, off"
                 :: "v"(p), "v"(v) : "memory");
}
__device__ __forceinline__ void store_flag_mall(int* p, int v) {
    asm volatile("global_store_dword %0, %1, off sc0 sc1"
                 :: "v"(p), "v"(v) : "memory");
}

// ---------------- LSTM persistent kernel ----------------
// 256 blocks, 1/CU (96 KiB LDS). Static roles: bg = blk&7 (32 batch rows),
// hg = blk>>3 (16 hidden cols). Under round-robin dispatch each bg-group is
// co-XCD (performance heuristic ONLY). Weights slice staged once in LDS as
// W^T fragments; swapped-operand MFMA (gates^T = W^T * in^T) makes each lane
// own 4 CONSECUTIVE hidden cols of one batch row -> one 8B packed h store.
// Per-step sync: per-wave epoch flags, double-published (L2 + MALL); no
// atomics, no __syncthreads in the loop, no cross-XCD wait on liveness path.
__global__ void __launch_bounds__(128, 1)
lstm_persist(const float* __restrict__ x,
             const float* __restrict__ wk,
             const float* __restrict__ bias,
             unsigned short* __restrict__ hbuf,       // [2][B][H] local copy
             unsigned short* __restrict__ hbuf_mall,  // [2][B][H] MALL copy
             int* __restrict__ flags_loc,             // [8][64] epochs, 64B stride
             int* __restrict__ flags_mall)
{
    extern __shared__ unsigned short lds_w[];     // [96 frag][64 lane][8]
    const int tid = threadIdx.x;
    const int blk = blockIdx.x;
    const int bg  = blk & 7;
    const int hg  = blk >> 3;
    const int bb  = bg * 32;
    const int hh  = hg * 16;

    // ---- preload weights into LDS as W^T fragments (once) ----
    // frag f=kt*4+g; lane l; elem j -> W[kt*32+(l>>4)*8+j][g*512+hh+(l&15)]
    for (int f = 0; f < 96; ++f) {
        const int kt = f >> 2, g = f & 3;
        for (int idx = tid; idx < 512; idx += 128) {
            const int c  = idx & 15;
            const int hi = (idx >> 4) & 3;
            const int j  = idx >> 6;
            const int k  = kt * 32 + hi * 8 + j;
            const int col = g * 512 + hh + c;
            lds_w[(f * 64 + hi * 16 + c) * 8 + j] = f2bf(wk[(size_t)k * 2048 + col]);
        }
    }
    __syncthreads();

    const int w    = tid >> 6;        // wave: batch rows [bb+w*16, +16)
    const int lane = tid & 63;
    const int lc   = lane & 15;
    const int lk   = lane >> 4;

    // biases for this lane's 4 hidden cols (hh + lk*4 + j), per gate
    const f32x4 bi  = *(const f32x4*)(bias + 0 * 512 + hh + lk * 4);
    const f32x4 bj  = *(const f32x4*)(bias + 1 * 512 + hh + lk * 4);
    f32x4       bf_ = *(const f32x4*)(bias + 2 * 512 + hh + lk * 4);
    const f32x4 bo  = *(const f32x4*)(bias + 3 * 512 + hh + lk * 4);
    bf_ = bf_ + 1.0f;                                  // FORGET_BIAS

    f32x4 c_frag = {0.f, 0.f, 0.f, 0.f};

    const int arow = bb + w * 16 + lc;                 // batch row (loads & store)
    const float* xbase = x + (size_t)arow * E_DIM + lk * 8;

    int* fg_l = flags_loc  + bg * 1024;                // 64 flags, 64B apart
    int* fg_m = flags_mall + bg * 1024;
    const int* fpoll_l = fg_l + ((lane & 31) * 2 + w) * 16;  // same-w producers
    const int* fpoll_m = fg_m + ((lane & 31) * 2 + w) * 16;
    int* fmine_l = fg_l + (hg * 2 + w) * 16;
    int* fmine_m = fg_m + (hg * 2 + w) * 16;

    for (int t = 0; t < T_DIM; ++t) {
        // ---- 1. x part first (independent of h_t) ----
        f32x4 a0 = {0.f,0.f,0.f,0.f}, a1 = a0, a2 = a0, a3 = a0;
        const float* xr = xbase + (size_t)t * (B_DIM * E_DIM);
        #pragma unroll
        for (int kt = 0; kt < 8; ++kt) {
            const float* p = xr + kt * 32;
            const f32x4 lo = *(const f32x4*)p;
            const f32x4 hi = *(const f32x4*)(p + 4);
            short8 a;
            a[0]=cvt_bf(lo[0]); a[1]=cvt_bf(lo[1]); a[2]=cvt_bf(lo[2]); a[3]=cvt_bf(lo[3]);
            a[4]=cvt_bf(hi[0]); a[5]=cvt_bf(hi[1]); a[6]=cvt_bf(hi[2]); a[7]=cvt_bf(hi[3]);
            const unsigned short* wp = lds_w + ((size_t)(kt * 4) * 64 + lane) * 8;
            a0 = __builtin_amdgcn_mfma_f32_16x16x32_bf16(*(const short8*)(wp +    0), a, a0, 0,0,0);
            a1 = __builtin_amdgcn_mfma_f32_16x16x32_bf16(*(const short8*)(wp +  512), a, a1, 0,0,0);
            a2 = __builtin_amdgcn_mfma_f32_16x16x32_bf16(*(const short8*)(wp + 1024), a, a2, 0,0,0);
            a3 = __builtin_amdgcn_mfma_f32_16x16x32_bf16(*(const short8*)(wp + 1536), a, a3, 0,0,0);
        }

        if (t > 0) {
            // ---- 2. wait for producers: bounded LOCAL spin, then MALL ----
            const int tt = t;
            bool got = false;
            #pragma unroll 1
            for (int it = 0; it < 16; ++it) {
                if (__all(got)) break;
                if (!got) got = (load_flag_loc(fpoll_l) >= tt);
            }
            const unsigned long long lmask = __ballot(got);   // bit p: producer p local-ready
            #pragma unroll 1
            while (!__all(got)) {
                if (!got) got = (load_flag_mall(fpoll_m) >= tt);
                if (!got) __builtin_amdgcn_s_sleep(1);
            }
            __builtin_amdgcn_sched_barrier(0);

            // ---- 3. h loads: per-fragment source select (L2 vs MALL) ----
            const size_t base = (size_t)(t & 1) * (B_DIM * H_DIM)
                              + (size_t)arow * H_DIM + lk * 8;
            const unsigned short* hr_l = hbuf      + base;
            const unsigned short* hr_m = hbuf_mall + base;
            short8 hfr[16];
            #pragma unroll
            for (int k = 0; k < 16; ++k) {
                // fragment k spans h cols [k*32, k*32+32) = producers 2k, 2k+1
                const bool lok = ((lmask >> (2 * k)) & 3ull) == 3ull;
                if (lok) hfr[k] = load16_loc(hr_l + k * 32);
                else     hfr[k] = load16_mall(hr_m + k * 32);
            }

            asm volatile("s_waitcnt vmcnt(8)" ::: "memory");
            __builtin_amdgcn_sched_barrier(0);
            #pragma unroll
            for (int k = 0; k < 8; ++k) {
                const unsigned short* wp = lds_w + ((size_t)((8 + k) * 4) * 64 + lane) * 8;
                a0 = __builtin_amdgcn_mfma_f32_16x16x32_bf16(*(const short8*)(wp +    0), hfr[k], a0, 0,0,0);
                a1 = __builtin_amdgcn_mfma_f32_16x16x32_bf16(*(const short8*)(wp +  512), hfr[k], a1, 0,0,0);
                a2 = __builtin_amdgcn_mfma_f32_16x16x32_bf16(*(const short8*)(wp + 1024), hfr[k], a2, 0,0,0);
                a3 = __builtin_amdgcn_mfma_f32_16x16x32_bf16(*(const short8*)(wp + 1536), hfr[k], a3, 0,0,0);
            }
            asm volatile("s_waitcnt vmcnt(0)" ::: "memory");
            __builtin_amdgcn_sched_barrier(0);
            #pragma unroll
            for (int k = 8; k < 16; ++k) {
                const unsigned short* wp = lds_w + ((size_t)((8 + k) * 4) * 64 + lane) * 8;
                a0 = __builtin_amdgcn_mfma_f32_16x16x32_bf16(*(const short8*)(wp +    0), hfr[k], a0, 0,0,0);
                a1 = __builtin_amdgcn_mfma_f32_16x16x32_bf16(*(const short8*)(wp +  512), hfr[k], a1, 0,0,0);
                a2 = __builtin_amdgcn_mfma_f32_16x16x32_bf16(*(const short8*)(wp + 1024), hfr[k], a2, 0,0,0);
                a3 = __builtin_amdgcn_mfma_f32_16x16x32_bf16(*(const short8*)(wp + 1536), hfr[k], a3, 0,0,0);
            }
        }

        // ---- 4. lane-local LSTM update; 4 consecutive hidden cols -> 8B ----
        unsigned short hu[4];
        #pragma unroll
        for (int j = 0; j < 4; ++j) {
            const float iv = a0[j] + bi[j];
            const float jv = a1[j] + bj[j];
            const float fv = a2[j] + bf_[j];
            const float ov = a3[j] + bo[j];
            const float cn = sigmoidf_(fv) * c_frag[j] + sigmoidf_(iv) * tanhf_(jv);
            c_frag[j] = cn;
            hu[j] = f2bf(sigmoidf_(ov) * tanhf_(cn));
        }
        uint2v pk;
        pk[0] = (unsigned)hu[0] | ((unsigned)hu[1] << 16);
        pk[1] = (unsigned)hu[2] | ((unsigned)hu[3] << 16);
        const size_t hoff = (size_t)((t + 1) & 1) * (B_DIM * H_DIM)
                          + (size_t)arow * H_DIM + hh + lk * 4;
        store8_loc(hbuf + hoff, pk);          // fast path (own XCD L2)
        store8_mall(hbuf_mall + hoff, pk);    // always-arrives path (MALL)

        // ---- 5. per-wave release: drain BOTH stores, publish both flags ----
        asm volatile("s_waitcnt vmcnt(0)" ::: "memory");
        if (lane == 0) {
            store_flag_loc(fmine_l, t + 1);
            store_flag_mall(fmine_m, t + 1);
        }
    }
}

// ---------------- final projection: out = h_last @ W_out + b_out ----------------
__global__ void __launch_bounds__(256)
proj_gemm(const unsigned short* __restrict__ h,   // [256][512] bf16 (hbuf_mall[0])
          const float* __restrict__ wout,         // [512][V]
          const float* __restrict__ bout,         // [V]
          float* __restrict__ out)                // [256][V]
{
    const int tid  = threadIdx.x;
    const int w    = tid >> 6;
    const int lane = tid & 63;
    const int lc   = lane & 15;
    const int lk   = lane >> 4;
    const int n0   = blockIdx.x * 128 + w * 32;

    f32x4 acc[16][2];
    #pragma unroll
    for (int mt = 0; mt < 16; ++mt) {
        acc[mt][0] = (f32x4){0.f,0.f,0.f,0.f};
        acc[mt][1] = (f32x4){0.f,0.f,0.f,0.f};
    }
    int ncl[2];
    ncl[0] = min(n0 + lc,      V_DIM - 1);
    ncl[1] = min(n0 + 16 + lc, V_DIM - 1);

    #pragma unroll 4
    for (int kt = 0; kt < 16; ++kt) {
        short8 bfr[2];
        #pragma unroll
        for (int nt = 0; nt < 2; ++nt) {
            #pragma unroll
            for (int j = 0; j < 8; ++j) {
                const int k = kt * 32 + lk * 8 + j;
                bfr[nt][j] = (short)f2bf(wout[(size_t)k * V_DIM + ncl[nt]]);
            }
        }
        #pragma unroll
        for (int mt = 0; mt < 16; ++mt) {
            const short8 a = *(const short8*)(h + (size_t)(mt * 16 + lc) * H_DIM
                                                + kt * 32 + lk * 8);
            acc[mt][0] = __builtin_amdgcn_mfma_f32_16x16x32_bf16(a, bfr[0], acc[mt][0], 0,0,0);
            acc[mt][1] = __builtin_amdgcn_mfma_f32_16x16x32_bf16(a, bfr[1], acc[mt][1], 0,0,0);
        }
    }

    #pragma unroll
    for (int nt = 0; nt < 2; ++nt) {
        const int n = n0 + nt * 16 + lc;
        if (n < V_DIM) {
            const float bb = bout[n];
            #pragma unroll
            for (int mt = 0; mt < 16; ++mt)
                #pragma unroll
                for (int j = 0; j < 4; ++j)
                    out[(size_t)(mt * 16 + lk * 4 + j) * V_DIM + n] = acc[mt][nt][j] + bb;
        }
    }
}

extern "C" void kernel_launch(void* const* d_in, const int* in_sizes, int n_in,
                              void* d_out, int out_size, void* d_ws, size_t ws_size,
                              hipStream_t stream) {
    const float* x    = (const float*)d_in[0];
    const float* wk   = (const float*)d_in[1];
    const float* bias = (const float*)d_in[2];
    const float* wout = (const float*)d_in[3];
    const float* bout = (const float*)d_in[4];
    float* out = (float*)d_out;

    unsigned short* hbuf      = (unsigned short*)d_ws;                    // 512 KiB
    unsigned short* hbuf_mall = (unsigned short*)((char*)d_ws + (512<<10));
    int* flags_loc  = (int*)((char*)d_ws + (1024 << 10));                 // 32 KiB
    int* flags_mall = (int*)((char*)d_ws + (1024 << 10) + (32 << 10));    // 32 KiB

    // flags = 0 every call (graph-replay safe). hbufs need no init: t=0
    // skips the h-GEMM (h0 == 0) and fully writes slot 1 of both copies.
    hipMemsetAsync(flags_loc, 0, 64 << 10, stream);

    hipFuncSetAttribute((const void*)lstm_persist,
                        hipFuncAttributeMaxDynamicSharedMemorySize, 96 * 1024);

    hipLaunchKernelGGL(lstm_persist, dim3(256), dim3(128), 96 * 1024, stream,
                       x, wk, bias, hbuf, hbuf_mall, flags_loc, flags_mall);
    // h_last is in hbuf_mall[0] — MALL copy, visible to the next dispatch
    // regardless of per-XCD L2 writeback behavior.
    hipLaunchKernelGGL(proj_gemm, dim3((V_DIM + 127) / 128), dim3(256), 0, stream,
                       hbuf_mall, wout, bout, out);
}